// Round 2
// baseline (12634.879 us; speedup 1.0000x reference)
//
#include <hip/hip_runtime.h>
#include <math.h>

#define KK 128
#define NTT 128
#define PMAXF 10.0f
#define SP 0.1f          // SIGMA / PMAX

typedef float2 c32;

__device__ __forceinline__ c32 cmul(c32 a, c32 b){
    return make_float2(a.x*b.x - a.y*b.y, a.x*b.y + a.y*b.x);
}
__device__ __forceinline__ c32 cmulc(c32 a, c32 b){ // a * conj(b)
    return make_float2(a.x*b.x + a.y*b.y, a.y*b.x - a.x*b.y);
}
__device__ __forceinline__ c32 cinv(c32 a){
    float d = 1.0f/(a.x*a.x + a.y*a.y);
    return make_float2(a.x*d, -a.y*d);
}

// ---------------- tr_vv of the raw input V (layer 0 only) ----------------
__global__ void k_trvv(const float* __restrict__ V0, float* __restrict__ out){
    float s = 0.f;
    for (int e = blockIdx.x*blockDim.x + threadIdx.x; e < 2*KK*NTT; e += gridDim.x*blockDim.x){
        float v = V0[e]; s += v*v;
    }
    __shared__ float red[4];
    for (int d = 32; d; d >>= 1) s += __shfl_down(s, d);
    int lane = threadIdx.x & 63, w = threadIdx.x >> 6;
    if (!lane) red[w] = s;
    __syncthreads();
    if (!threadIdx.x){
        float t = red[0] + red[1] + red[2] + red[3];
        atomicAdd(out, t);
    }
}

// ---------------- stage 1: P row + per-k scalar chain ----------------
__global__ void k_stage1(const float* __restrict__ Hre, const float* __restrict__ Him,
                         const float* __restrict__ V0re, const float* __restrict__ V0im,
                         const float2* __restrict__ VN, int use_vn,
                         const float* __restrict__ pw2prev,  // null for layer 0
                         const float* __restrict__ trvvp,    // used when layer 0
                         const float* __restrict__ u1, const float* __restrict__ u3,
                         const float* __restrict__ u4, const float* __restrict__ w1,
                         const float* __restrict__ w3,
                         float* __restrict__ wre, float* __restrict__ wim,
                         float* __restrict__ sre, float* __restrict__ sim,
                         float* __restrict__ sumw)
{
    int k = blockIdx.x, j = threadIdx.x;
    __shared__ float hre_s[NTT], him_s[NTT];
    __shared__ float redq[NTT];
    __shared__ c32 pkk_s;
    hre_s[j] = Hre[k*NTT + j];
    him_s[j] = Him[k*NTT + j];
    __syncthreads();

    float g = 1.0f;
    if (pw2prev) g = sqrtf(PMAXF / *pw2prev);

    float pre = 0.f, pim = 0.f;
    if (use_vn){
        const float2* vr = VN + j*NTT;
        #pragma unroll 4
        for (int n = 0; n < NTT; n++){
            float2 v = vr[n];
            pre += hre_s[n]*v.x - him_s[n]*v.y;
            pim += hre_s[n]*v.y + him_s[n]*v.x;
        }
    } else {
        const float* vr = V0re + j*NTT;
        const float* vi = V0im + j*NTT;
        #pragma unroll 4
        for (int n = 0; n < NTT; n++){
            float a = vr[n], b = vi[n];
            pre += hre_s[n]*a - him_s[n]*b;
            pim += hre_s[n]*b + him_s[n]*a;
        }
    }
    pre *= g; pim *= g;
    if (j == k) pkk_s = make_float2(pre, pim);
    redq[j] = pre*pre + pim*pim;
    __syncthreads();
    for (int d = 64; d; d >>= 1){
        if (j < d) redq[j] += redq[j + d];
        __syncthreads();
    }
    if (j == 0){
        float trvv = pw2prev ? PMAXF : *trvvp;
        float A = SP*trvv + redq[0];
        float invA = 1.0f/A;
        c32 p1 = make_float2(u1[k], u1[KK + k]);
        c32 p3 = make_float2(u3[k], u3[KK + k]);
        c32 p4 = make_float2(u4[k], u4[KK + k]);
        c32 Ainv = make_float2(p1.x*invA + 0.01f*p3.x, p1.y*invA + 0.01f*p3.y);
        c32 Pkk = pkk_s;
        c32 U = cmul(Ainv, Pkk); U.x += p4.x; U.y += p4.y;
        c32 t = cmulc(Pkk, U);                  // Pkk * conj(U)
        c32 E = make_float2(1.0f - t.x, -t.y);
        c32 iE = cinv(E);
        c32 q1 = make_float2(w1[k], w1[KK + k]);
        c32 q3 = make_float2(w3[k], w3[KK + k]);
        c32 W = cmul(q1, iE);
        W.x = 0.1f*W.x + 0.01f*q3.x;
        W.y = 0.1f*W.y + 0.01f*q3.y;
        float u2 = U.x*U.x + U.y*U.y;
        c32 wk = make_float2(u2*W.x, u2*W.y);
        c32 sk = cmul(U, W);
        wre[k] = wk.x; wim[k] = wk.y;
        sre[k] = sk.x; sim[k] = sk.y;
        atomicAdd(&sumw[0], wk.x);
        atomicAdd(&sumw[1], wk.y);
    }
}

// ---------------- build B = 0.1*sum_w*I + H^H diag(w) H ----------------
__global__ void k_bbuild(const float* __restrict__ Hre, const float* __restrict__ Him,
                         const float* __restrict__ wre, const float* __restrict__ wim,
                         const float* __restrict__ sumw, float2* __restrict__ B)
{
    int n = blockIdx.x, m = threadIdx.x;
    __shared__ float cr[KK], ci[KK];
    {
        int k = m;
        c32 h = make_float2(Hre[k*NTT + n], -Him[k*NTT + n]); // conj(H[k,n])
        c32 wk = make_float2(wre[k], wim[k]);
        c32 t = cmul(h, wk);
        cr[k] = t.x; ci[k] = t.y;
    }
    __syncthreads();
    float br = 0.f, bi = 0.f;
    #pragma unroll 4
    for (int k = 0; k < KK; k++){
        float hr = Hre[k*NTT + m], hi = Him[k*NTT + m];
        br += cr[k]*hr - ci[k]*hi;
        bi += cr[k]*hi + ci[k]*hr;
    }
    if (n == m){ br += SP*sumw[0]; bi += SP*sumw[1]; }
    B[n*NTT + m] = make_float2(br, bi);
}

// ---------------- register-resident LU with logical partial pivoting ----------------
// 256 threads: thread (rb, cb) owns rows 4*rb..4*rb+3, cols 16*cb..16*cb+15 in VGPRs.
// No physical row swaps: elimination order tracked via pos[]; rows written to BT at
// their elimination position, so k_solve's semantics (BT/rc/perm) are unchanged.
// Lazy L scaling: col-i entries keep numerators; rc[i] = 1/pivot applied at solve.
__global__ void __launch_bounds__(256, 1) k_lu2(const float2* __restrict__ B,
                                                float2* __restrict__ BT,
                                                float2* __restrict__ rcg,
                                                int* __restrict__ permg)
{
    __shared__ float4 colv[KK];      // {re, im, score, idx}; score=-1e30 when eliminated
    __shared__ float4 urow4[8*9];    // pivot row, 2 complex per float4, stride-9 padded
    __shared__ float2 rc_s[KK];
    __shared__ int    perm_s[KK];

    int t  = threadIdx.x;
    int cb = t & 7;          // col block: cols [16*cb, 16*cb+16)
    int rb = t >> 3;         // row block: rows [4*rb, 4*rb+4)
    int r0 = rb*4;
    int cbase = cb*16;

    float2 a[4][16];
    const float4* B4 = (const float4*)B;
    #pragma unroll
    for (int s = 0; s < 4; ++s){
        #pragma unroll
        for (int k = 0; k < 8; ++k){
            float4 q = B4[(size_t)(r0 + s)*64 + cb*8 + k];
            a[s][2*k]   = make_float2(q.x, q.y);
            a[s][2*k+1] = make_float2(q.z, q.w);
        }
    }
    bool e[4] = {false, false, false, false};
    int pos[4] = {0, 0, 0, 0};

    // initial gather of column 0
    if (cb == 0){
        #pragma unroll
        for (int s = 0; s < 4; ++s){
            float2 v = a[s][0];
            colv[r0 + s] = make_float4(v.x, v.y, fabsf(v.x) + fabsf(v.y), (float)(r0 + s));
        }
    }
    __syncthreads();

    #pragma unroll 1
    for (int p = 0; p < 8; ++p){
        #pragma unroll
        for (int jj = 0; jj < 16; ++jj){
            const int i = p*16 + jj;

            // ---- phase 1: pivot search (redundant per wave), rc, m-values ----
            int l = t & 63;
            float4 c0 = colv[l], c1 = colv[l + 64];
            float sc; int idx;
            {
                float s0 = c0.z, s1 = c1.z;
                int i0 = (int)c0.w, i1 = (int)c1.w;
                if (s1 > s0 || (s1 == s0 && i1 < i0)){ sc = s1; idx = i1; }
                else                                  { sc = s0; idx = i0; }
            }
            #pragma unroll
            for (int d = 32; d; d >>= 1){
                float os = __shfl_xor(sc, d);
                int   oi = __shfl_xor(idx, d);
                if (os > sc || (os == sc && oi < idx)){ sc = os; idx = oi; }
            }
            const int piv = idx;
            float4 pv4 = colv[piv];
            float rin = 1.0f/(pv4.x*pv4.x + pv4.y*pv4.y);
            float2 rc = make_float2(pv4.x*rin, -pv4.y*rin);

            #pragma unroll
            for (int s = 0; s < 4; ++s){
                if (r0 + s == piv){ e[s] = true; pos[s] = i; }
            }
            if (t == 0){ rc_s[i] = rc; perm_s[i] = piv; }

            float2 m[4];
            #pragma unroll
            for (int s = 0; s < 4; ++s){
                float4 cv = colv[r0 + s];
                float2 num = make_float2(cv.x, cv.y);
                float2 mm = cmul(num, rc);
                m[s] = e[s] ? make_float2(0.f, 0.f) : mm;
            }

            // ---- phase 2: pivot-row broadcast (one wave, 8 lanes) ----
            if (rb == (piv >> 2)){
                int ps = piv & 3;
                #pragma unroll
                for (int k = 0; k < 8; ++k){
                    float2 x0a = (ps & 1) ? a[1][2*k]   : a[0][2*k];
                    float2 x0b = (ps & 1) ? a[3][2*k]   : a[2][2*k];
                    float2 u0  = (ps & 2) ? x0b : x0a;
                    float2 x1a = (ps & 1) ? a[1][2*k+1] : a[0][2*k+1];
                    float2 x1b = (ps & 1) ? a[3][2*k+1] : a[2][2*k+1];
                    float2 u1  = (ps & 2) ? x1b : x1a;
                    urow4[cb*9 + k] = make_float4(u0.x, u0.y, u1.x, u1.y);
                }
            }
            __syncthreads();

            // ---- phase 3: rank-1 update in registers ----
            float2 u[16];
            #pragma unroll
            for (int k = 0; k < 8; ++k){
                float4 q = urow4[cb*9 + k];
                u[2*k]   = make_float2(q.x, q.y);
                u[2*k+1] = make_float2(q.z, q.w);
            }
            #pragma unroll
            for (int c = 0; c < 16; ++c){
                if (cbase + c <= i) u[c] = make_float2(0.f, 0.f);  // freeze cols <= i
            }
            #pragma unroll
            for (int s = 0; s < 4; ++s){
                #pragma unroll
                for (int c = 0; c < 16; ++c){
                    float2 mu = cmul(m[s], u[c]);
                    a[s][c].x -= mu.x;
                    a[s][c].y -= mu.y;
                }
            }

            // ---- gather next column (post-update values) ----
            if (i < 127){
                if (cb == ((i + 1) >> 4)){
                    const int ridx = (jj + 1) & 15;
                    #pragma unroll
                    for (int s = 0; s < 4; ++s){
                        float2 v = a[s][ridx];
                        float scn = e[s] ? -1e30f : (fabsf(v.x) + fabsf(v.y));
                        colv[r0 + s] = make_float4(v.x, v.y, scn, (float)(r0 + s));
                    }
                }
            }
            __syncthreads();
        }
    }

    // ---- write out in elimination order (column-major BT) ----
    #pragma unroll
    for (int s = 0; s < 4; ++s){
        int ps_ = pos[s];
        #pragma unroll
        for (int c = 0; c < 16; ++c){
            BT[(size_t)(cbase + c)*KK + ps_] = a[s][c];
        }
    }
    if (t < KK){ rcg[t] = rc_s[t]; permg[t] = perm_s[t]; }
}

// ---------------- triangular solves: block c solves B x = conj(H[c,:])^T ----------------
__global__ void k_solve(const float2* __restrict__ BT, const float2* __restrict__ rcg,
                        const int* __restrict__ permg,
                        const float* __restrict__ Hre, const float* __restrict__ Him,
                        float2* __restrict__ X)
{
    int c = blockIdx.x;
    int lane = threadIdx.x;
    __shared__ float2 rc_s[KK];
    rc_s[lane] = rcg[lane];
    rc_s[lane + 64] = rcg[lane + 64];
    int r0 = lane, r1 = lane + 64;
    int o0 = permg[r0], o1 = permg[r1];
    float2 b0 = make_float2(Hre[c*NTT + o0], -Him[c*NTT + o0]);
    float2 b1 = make_float2(Hre[c*NTT + o1], -Him[c*NTT + o1]);
    __syncthreads();

    float2 cur0[8], cur1[8];
    // -------- forward: L (unit diag, lazy scaled) --------
    #pragma unroll
    for (int jj = 0; jj < 8; jj++){ cur0[jj] = BT[jj*NTT + r0]; cur1[jj] = BT[jj*NTT + r1]; }
    for (int ib = 0; ib < 16; ib++){
        float2 n0[8], n1[8];
        if (ib < 15){
            int nb = (ib + 1)*8;
            #pragma unroll
            for (int jj = 0; jj < 8; jj++){ n0[jj] = BT[(nb + jj)*NTT + r0]; n1[jj] = BT[(nb + jj)*NTT + r1]; }
        }
        #pragma unroll
        for (int jj = 0; jj < 8; jj++){
            int i = ib*8 + jj;
            float xr, xi;
            if (i < 64){ xr = __shfl(b0.x, i);      xi = __shfl(b0.y, i); }
            else       { xr = __shfl(b1.x, i - 64); xi = __shfl(b1.y, i - 64); }
            float2 rc = rc_s[i];
            float tr = rc.x*xr - rc.y*xi, ti = rc.x*xi + rc.y*xr;
            float2 l0 = cur0[jj], l1 = cur1[jj];
            if (r0 > i){ b0.x -= l0.x*tr - l0.y*ti; b0.y -= l0.x*ti + l0.y*tr; }
            if (r1 > i){ b1.x -= l1.x*tr - l1.y*ti; b1.y -= l1.x*ti + l1.y*tr; }
        }
        if (ib < 15){
            #pragma unroll
            for (int jj = 0; jj < 8; jj++){ cur0[jj] = n0[jj]; cur1[jj] = n1[jj]; }
        }
    }
    // -------- backward: U --------
    #pragma unroll
    for (int jj = 0; jj < 8; jj++){ cur0[jj] = BT[(120 + jj)*NTT + r0]; cur1[jj] = BT[(120 + jj)*NTT + r1]; }
    for (int ib = 15; ib >= 0; ib--){
        float2 n0[8], n1[8];
        if (ib > 0){
            int nb = (ib - 1)*8;
            #pragma unroll
            for (int jj = 0; jj < 8; jj++){ n0[jj] = BT[(nb + jj)*NTT + r0]; n1[jj] = BT[(nb + jj)*NTT + r1]; }
        }
        #pragma unroll
        for (int jj = 7; jj >= 0; jj--){
            int i = ib*8 + jj;
            float yr, yi;
            if (i < 64){ yr = __shfl(b0.x, i);      yi = __shfl(b0.y, i); }
            else       { yr = __shfl(b1.x, i - 64); yi = __shfl(b1.y, i - 64); }
            float2 rc = rc_s[i];
            float xr = rc.x*yr - rc.y*yi, xi = rc.x*yi + rc.y*yr;
            if (r0 == i){ b0.x = xr; b0.y = xi; }
            if (r1 == i){ b1.x = xr; b1.y = xi; }
            float2 u0 = cur0[jj], u1v = cur1[jj];
            if (r0 < i){ b0.x -= u0.x*xr - u0.y*xi; b0.y -= u0.x*xi + u0.y*xr; }
            if (r1 < i){ b1.x -= u1v.x*xr - u1v.y*xi; b1.y -= u1v.x*xi + u1v.y*xr; }
        }
        if (ib > 0){
            #pragma unroll
            for (int jj = 0; jj < 8; jj++){ cur0[jj] = n0[jj]; cur1[jj] = n1[jj]; }
        }
    }
    X[c*NTT + r0] = b0;
    X[c*NTT + r1] = b1;
}

// ---------------- streaming matvecs: y_k = vp2[k] x_k ; z_k = vp4[k] conj(h_k) ----------------
__global__ void k_matvec(const float* __restrict__ p2re, const float* __restrict__ p2im,
                         const float* __restrict__ p4re, const float* __restrict__ p4im,
                         const float2* __restrict__ X,
                         const float* __restrict__ Hre, const float* __restrict__ Him,
                         float2* __restrict__ Y, float2* __restrict__ Z)
{
    int b = blockIdx.x;
    int k = b >> 1, rh = b & 1;
    int t = threadIdx.x;
    __shared__ float2 xv[NTT], hv[NTT];
    if (t < NTT){
        xv[t] = X[k*NTT + t];
        hv[t] = make_float2(Hre[k*NTT + t], -Him[k*NTT + t]);
    }
    __syncthreads();
    int which = t >> 7, u = t & 127;
    int row = rh*64 + (u >> 1), ch = u & 1;
    size_t base = (size_t)k*16384 + (size_t)row*128 + (size_t)ch*64;
    const float* mre = (which ? p4re : p2re) + base;
    const float* mim = (which ? p4im : p2im) + base;
    const float2* vv = (which ? hv : xv) + ch*64;
    float ar = 0.f, ai = 0.f;
    #pragma unroll 4
    for (int cidx = 0; cidx < 64; cidx++){
        float r_ = mre[cidx], i_ = mim[cidx];
        float2 v = vv[cidx];
        ar += r_*v.x - i_*v.y;
        ai += r_*v.y + i_*v.x;
    }
    ar += __shfl_xor(ar, 1);
    ai += __shfl_xor(ai, 1);
    if (ch == 0){
        (which ? Z : Y)[k*NTT + row] = make_float2(ar, ai);
    }
}

// ---------------- combine (mid layers): Vn = s*(y + 0.01 z) + vp1 ; accumulate |Vn|^2 ----------------
__global__ void k_combine(const float2* __restrict__ Y, const float2* __restrict__ Z,
                          const float* __restrict__ sre, const float* __restrict__ sim,
                          const float* __restrict__ p1re, const float* __restrict__ p1im,
                          float2* __restrict__ VN, float* __restrict__ pw2)
{
    float acc = 0.f;
    for (int e = blockIdx.x*blockDim.x + threadIdx.x; e < KK*NTT; e += gridDim.x*blockDim.x){
        int k = e >> 7;
        c32 s = make_float2(sre[k], sim[k]);
        float2 y = Y[e], z = Z[e];
        y.x += 0.01f*z.x; y.y += 0.01f*z.y;
        c32 v = cmul(s, y);
        v.x += p1re[e]; v.y += p1im[e];
        VN[e] = v;
        acc += v.x*v.x + v.y*v.y;
    }
    __shared__ float red[4];
    for (int d = 32; d; d >>= 1) acc += __shfl_down(acc, d);
    int lane = threadIdx.x & 63, w = threadIdx.x >> 6;
    if (!lane) red[w] = acc;
    __syncthreads();
    if (!threadIdx.x) atomicAdd(pw2, red[0] + red[1] + red[2] + red[3]);
}

// ---------------- final layer: Vn = s * x ----------------
__global__ void k_finout(const float2* __restrict__ X,
                         const float* __restrict__ sre, const float* __restrict__ sim,
                         float2* __restrict__ VN, float* __restrict__ pw2)
{
    float acc = 0.f;
    for (int e = blockIdx.x*blockDim.x + threadIdx.x; e < KK*NTT; e += gridDim.x*blockDim.x){
        int k = e >> 7;
        c32 s = make_float2(sre[k], sim[k]);
        c32 v = cmul(s, X[e]);
        VN[e] = v;
        acc += v.x*v.x + v.y*v.y;
    }
    __shared__ float red[4];
    for (int d = 32; d; d >>= 1) acc += __shfl_down(acc, d);
    int lane = threadIdx.x & 63, w = threadIdx.x >> 6;
    if (!lane) red[w] = acc;
    __syncthreads();
    if (!threadIdx.x) atomicAdd(pw2, red[0] + red[1] + red[2] + red[3]);
}

// ---------------- output write (normalized, split planes) ----------------
__global__ void k_write(const float2* __restrict__ VN, const float* __restrict__ pw2,
                        float* __restrict__ out)
{
    float gsc = sqrtf(PMAXF / *pw2);
    for (int e = blockIdx.x*blockDim.x + threadIdx.x; e < KK*NTT; e += gridDim.x*blockDim.x){
        float2 v = VN[e];
        out[e] = gsc*v.x;
        out[KK*NTT + e] = gsc*v.y;
    }
}

extern "C" void kernel_launch(void* const* d_in, const int* in_sizes, int n_in,
                              void* d_out, int out_size, void* d_ws, size_t ws_size,
                              hipStream_t stream)
{
    const float* V0  = (const float*)d_in[0];
    const float* H   = (const float*)d_in[1];
    const float* mu1 = (const float*)d_in[2];
    const float* mu3 = (const float*)d_in[3];
    const float* mu4 = (const float*)d_in[4];
    const float* mw1 = (const float*)d_in[5];
    const float* mw3 = (const float*)d_in[6];
    const float* mv1 = (const float*)d_in[7];
    const float* mv2 = (const float*)d_in[8];
    const float* mv4 = (const float*)d_in[9];
    const float* fu1 = (const float*)d_in[10];
    const float* fu3 = (const float*)d_in[11];
    const float* fu4 = (const float*)d_in[12];
    const float* fw1 = (const float*)d_in[13];
    const float* fw3 = (const float*)d_in[14];

    float* ws = (float*)d_ws;
    float*  acc  = ws;                       // [9][4]: sumw_re, sumw_im, pw2, pad ; trvv at ws[40]
    float*  wre  = ws + 64;
    float*  wim  = ws + 192;
    float*  sre  = ws + 320;
    float*  sim  = ws + 448;
    float2* B    = (float2*)(ws + 1024);     // 16384 complex
    float2* rc   = (float2*)(ws + 33792);    // 128
    int*    perm = (int*)  (ws + 34048);     // 128
    float2* X    = (float2*)(ws + 34176);    // 16384
    float2* Y    = (float2*)(ws + 66944);    // 16384
    float2* Z    = (float2*)(ws + 99712);    // 16384
    float2* VN   = (float2*)(ws + 132480);   // 16384
    float2* BT   = (float2*)(ws + 165248);   // 16384

    hipMemsetAsync(ws, 0, 64*sizeof(float), stream);
    k_trvv<<<64, 256, 0, stream>>>(V0, ws + 40);

    const float* Hre = H;
    const float* Him = H + 16384;

    for (int l = 0; l < 9; l++){
        bool fin = (l == 8);
        const float* u1 = fin ? fu1 : mu1 + (size_t)l*256;
        const float* u3 = fin ? fu3 : mu3 + (size_t)l*256;
        const float* u4 = fin ? fu4 : mu4 + (size_t)l*256;
        const float* w1 = fin ? fw1 : mw1 + (size_t)l*256;
        const float* w3 = fin ? fw3 : mw3 + (size_t)l*256;

        k_stage1<<<128, 128, 0, stream>>>(Hre, Him, V0, V0 + 16384, VN, (l > 0) ? 1 : 0,
                                          (l > 0) ? (acc + (l - 1)*4 + 2) : nullptr,
                                          ws + 40,
                                          u1, u3, u4, w1, w3,
                                          wre, wim, sre, sim, acc + l*4);
        k_bbuild<<<128, 128, 0, stream>>>(Hre, Him, wre, wim, acc + l*4, B);
        k_lu2<<<1, 256, 0, stream>>>(B, BT, rc, perm);
        k_solve<<<128, 64, 0, stream>>>(BT, rc, perm, Hre, Him, X);

        if (!fin){
            const float* p2 = mv2 + (size_t)l*4194304;
            const float* p4 = mv4 + (size_t)l*4194304;
            const float* p1 = mv1 + (size_t)l*32768;
            k_matvec<<<256, 256, 0, stream>>>(p2, p2 + 2097152, p4, p4 + 2097152,
                                              X, Hre, Him, Y, Z);
            k_combine<<<64, 256, 0, stream>>>(Y, Z, sre, sim, p1, p1 + 16384,
                                              VN, acc + l*4 + 2);
        } else {
            k_finout<<<64, 256, 0, stream>>>(X, sre, sim, VN, acc + l*4 + 2);
            k_write<<<64, 256, 0, stream>>>(VN, acc + l*4 + 2, (float*)d_out);
        }
    }
}

// Round 3
// 1766.790 us; speedup vs baseline: 7.1513x; 7.1513x over previous
//
#include <hip/hip_runtime.h>
#include <math.h>

#define KK 128
#define NTT 128
#define PMAXF 10.0f
#define SP 0.1f          // SIGMA / PMAX
#define LUT 512
#define LDA 129          // LDS row stride (float2) — 4-way-conflict column reads

typedef float2 c32;

__device__ __forceinline__ c32 cmul(c32 a, c32 b){
    return make_float2(a.x*b.x - a.y*b.y, a.x*b.y + a.y*b.x);
}
__device__ __forceinline__ c32 cmulc(c32 a, c32 b){ // a * conj(b)
    return make_float2(a.x*b.x + a.y*b.y, a.y*b.x - a.x*b.y);
}
__device__ __forceinline__ c32 cinv(c32 a){
    float d = 1.0f/(a.x*a.x + a.y*a.y);
    return make_float2(a.x*d, -a.y*d);
}

// ---------------- tr_vv of the raw input V (layer 0 only) ----------------
__global__ void k_trvv(const float* __restrict__ V0, float* __restrict__ out){
    float s = 0.f;
    for (int e = blockIdx.x*blockDim.x + threadIdx.x; e < 2*KK*NTT; e += gridDim.x*blockDim.x){
        float v = V0[e]; s += v*v;
    }
    __shared__ float red[4];
    for (int d = 32; d; d >>= 1) s += __shfl_down(s, d);
    int lane = threadIdx.x & 63, w = threadIdx.x >> 6;
    if (!lane) red[w] = s;
    __syncthreads();
    if (!threadIdx.x){
        float t = red[0] + red[1] + red[2] + red[3];
        atomicAdd(out, t);
    }
}

// ---------------- stage 1: P row + per-k scalar chain ----------------
__global__ void k_stage1(const float* __restrict__ Hre, const float* __restrict__ Him,
                         const float* __restrict__ V0re, const float* __restrict__ V0im,
                         const float2* __restrict__ VN, int use_vn,
                         const float* __restrict__ pw2prev,  // null for layer 0
                         const float* __restrict__ trvvp,    // used when layer 0
                         const float* __restrict__ u1, const float* __restrict__ u3,
                         const float* __restrict__ u4, const float* __restrict__ w1,
                         const float* __restrict__ w3,
                         float* __restrict__ wre, float* __restrict__ wim,
                         float* __restrict__ sre, float* __restrict__ sim,
                         float* __restrict__ sumw)
{
    int k = blockIdx.x, j = threadIdx.x;
    __shared__ float hre_s[NTT], him_s[NTT];
    __shared__ float redq[NTT];
    __shared__ c32 pkk_s;
    hre_s[j] = Hre[k*NTT + j];
    him_s[j] = Him[k*NTT + j];
    __syncthreads();

    float g = 1.0f;
    if (pw2prev) g = sqrtf(PMAXF / *pw2prev);

    float pre = 0.f, pim = 0.f;
    if (use_vn){
        const float2* vr = VN + j*NTT;
        #pragma unroll 4
        for (int n = 0; n < NTT; n++){
            float2 v = vr[n];
            pre += hre_s[n]*v.x - him_s[n]*v.y;
            pim += hre_s[n]*v.y + him_s[n]*v.x;
        }
    } else {
        const float* vr = V0re + j*NTT;
        const float* vi = V0im + j*NTT;
        #pragma unroll 4
        for (int n = 0; n < NTT; n++){
            float a = vr[n], b = vi[n];
            pre += hre_s[n]*a - him_s[n]*b;
            pim += hre_s[n]*b + him_s[n]*a;
        }
    }
    pre *= g; pim *= g;
    if (j == k) pkk_s = make_float2(pre, pim);
    redq[j] = pre*pre + pim*pim;
    __syncthreads();
    for (int d = 64; d; d >>= 1){
        if (j < d) redq[j] += redq[j + d];
        __syncthreads();
    }
    if (j == 0){
        float trvv = pw2prev ? PMAXF : *trvvp;
        float A = SP*trvv + redq[0];
        float invA = 1.0f/A;
        c32 p1 = make_float2(u1[k], u1[KK + k]);
        c32 p3 = make_float2(u3[k], u3[KK + k]);
        c32 p4 = make_float2(u4[k], u4[KK + k]);
        c32 Ainv = make_float2(p1.x*invA + 0.01f*p3.x, p1.y*invA + 0.01f*p3.y);
        c32 Pkk = pkk_s;
        c32 U = cmul(Ainv, Pkk); U.x += p4.x; U.y += p4.y;
        c32 t = cmulc(Pkk, U);                  // Pkk * conj(U)
        c32 E = make_float2(1.0f - t.x, -t.y);
        c32 iE = cinv(E);
        c32 q1 = make_float2(w1[k], w1[KK + k]);
        c32 q3 = make_float2(w3[k], w3[KK + k]);
        c32 W = cmul(q1, iE);
        W.x = 0.1f*W.x + 0.01f*q3.x;
        W.y = 0.1f*W.y + 0.01f*q3.y;
        float u2 = U.x*U.x + U.y*U.y;
        c32 wk = make_float2(u2*W.x, u2*W.y);
        c32 sk = cmul(U, W);
        wre[k] = wk.x; wim[k] = wk.y;
        sre[k] = sk.x; sim[k] = sk.y;
        atomicAdd(&sumw[0], wk.x);
        atomicAdd(&sumw[1], wk.y);
    }
}

// ---------------- build B = 0.1*sum_w*I + H^H diag(w) H ----------------
__global__ void k_bbuild(const float* __restrict__ Hre, const float* __restrict__ Him,
                         const float* __restrict__ wre, const float* __restrict__ wim,
                         const float* __restrict__ sumw, float2* __restrict__ B)
{
    int n = blockIdx.x, m = threadIdx.x;
    __shared__ float cr[KK], ci[KK];
    {
        int k = m;
        c32 h = make_float2(Hre[k*NTT + n], -Him[k*NTT + n]); // conj(H[k,n])
        c32 wk = make_float2(wre[k], wim[k]);
        c32 t = cmul(h, wk);
        cr[k] = t.x; ci[k] = t.y;
    }
    __syncthreads();
    float br = 0.f, bi = 0.f;
    #pragma unroll 4
    for (int k = 0; k < KK; k++){
        float hr = Hre[k*NTT + m], hi = Him[k*NTT + m];
        br += cr[k]*hr - ci[k]*hi;
        bi += cr[k]*hi + ci[k]*hr;
    }
    if (n == m){ br += SP*sumw[0]; bi += SP*sumw[1]; }
    B[n*NTT + m] = make_float2(br, bi);
}

// ---------------- panel-blocked LU, no pivoting, LDS-resident ----------------
// 512 threads, 1 workgroup. Matrix in LDS [128][129] float2 (132 KB dynamic).
// Per 16-col panel: (A) 16 serial steps, 1 barrier each, updating only the
// in-panel sub-rectangle; (B1) triangular update of U-block rows (regs, 2 waves);
// (Msc) pre-scaled multipliers to LDS; (B2) rank-16 trailing update with the
// U-rows register-cached per column and Msc broadcast-read.
// Output: BT column-major with L numerators below diag (lazy scaling), rc = 1/piv,
// perm = identity — k_solve unchanged.
__global__ void __launch_bounds__(512, 1) k_lu3(const float2* __restrict__ B,
                                                float2* __restrict__ BT,
                                                float2* __restrict__ rcg,
                                                int* __restrict__ permg)
{
    extern __shared__ float2 As[];           // [128][LDA]
    __shared__ float2 rc_s[KK];
    __shared__ float2 Msc[112*16];
    int t = threadIdx.x;

    for (int e = t; e < KK*NTT; e += LUT){
        int r = e >> 7, c = e & 127;
        As[r*LDA + c] = B[e];
    }
    __syncthreads();

    for (int j = 0; j < 8; ++j){
        const int J0 = j*16;
        // ---- Phase A: factor panel columns [J0, J0+16) ----
        for (int ii = 0; ii < 16; ++ii){
            const int gi = J0 + ii;
            float2 piv = As[gi*LDA + gi];     // broadcast read
            float2 rc = cinv(piv);
            if (t == 0) rc_s[gi] = rc;
            const int w = 15 - ii;            // cols gi+1 .. J0+15
            const int nel = (127 - gi) * w;
            for (int e = t; e < nel; e += LUT){
                int r = gi + 1 + e / w;
                int c = gi + 1 + e % w;
                float2 m = cmul(As[r*LDA + gi], rc);
                float2 u = As[gi*LDA + c];
                float2 a = As[r*LDA + c];
                a.x -= m.x*u.x - m.y*u.y;
                a.y -= m.x*u.y + m.y*u.x;
                As[r*LDA + c] = a;
            }
            __syncthreads();
        }
        if (j == 7) break;
        const int T0 = J0 + 16;
        const int Rt = 128 - T0;

        // ---- Msc: m[r,i] = L_num[r][J0+i] * rc[J0+i] for trailing rows ----
        for (int e = t; e < Rt*16; e += LUT){
            int rp = e >> 4, i = e & 15;
            float2 l = As[(T0 + rp)*LDA + J0 + i];
            Msc[rp*16 + i] = cmul(l, rc_s[J0 + i]);
        }
        // ---- B1: triangular update of U-block rows J0+1..J0+15, cols >= T0 ----
        if (t < Rt){
            int c = T0 + t;
            float2 u[16];
            #pragma unroll
            for (int a2 = 0; a2 < 16; ++a2) u[a2] = As[(J0 + a2)*LDA + c];
            #pragma unroll
            for (int a2 = 1; a2 < 16; ++a2){
                #pragma unroll
                for (int i = 0; i < 16; ++i){
                    if (i < a2){
                        float2 m = cmul(As[(J0 + a2)*LDA + J0 + i], rc_s[J0 + i]);
                        u[a2].x -= m.x*u[i].x - m.y*u[i].y;
                        u[a2].y -= m.x*u[i].y + m.y*u[i].x;
                    }
                }
            }
            #pragma unroll
            for (int a2 = 1; a2 < 16; ++a2) As[(J0 + a2)*LDA + c] = u[a2];
        }
        __syncthreads();

        // ---- B2: rank-16 trailing update, rows/cols [T0,128) ----
        {
            int cl = t & 127;
            int g  = t >> 7;                  // 0..3 row groups
            if (cl < Rt){
                int c = T0 + cl;
                float2 u[16];
                #pragma unroll
                for (int i = 0; i < 16; ++i) u[i] = As[(J0 + i)*LDA + c];
                for (int r = T0 + g; r < 128; r += 4){
                    int rp = r - T0;
                    float2 a = As[r*LDA + c];
                    #pragma unroll
                    for (int i = 0; i < 16; ++i){
                        float2 m = Msc[rp*16 + i];   // broadcast (same addr per wave)
                        a.x -= m.x*u[i].x - m.y*u[i].y;
                        a.y -= m.x*u[i].y + m.y*u[i].x;
                    }
                    As[r*LDA + c] = a;
                }
            }
        }
        __syncthreads();
    }

    for (int e = t; e < KK*NTT; e += LUT){
        int c = e >> 7, r = e & 127;
        BT[e] = As[r*LDA + c];
    }
    if (t < KK){ rcg[t] = rc_s[t]; permg[t] = t; }
}

// ---------------- triangular solves: block c solves B x = conj(H[c,:])^T ----------------
__global__ void k_solve(const float2* __restrict__ BT, const float2* __restrict__ rcg,
                        const int* __restrict__ permg,
                        const float* __restrict__ Hre, const float* __restrict__ Him,
                        float2* __restrict__ X)
{
    int c = blockIdx.x;
    int lane = threadIdx.x;
    __shared__ float2 rc_s[KK];
    rc_s[lane] = rcg[lane];
    rc_s[lane + 64] = rcg[lane + 64];
    int r0 = lane, r1 = lane + 64;
    int o0 = permg[r0], o1 = permg[r1];
    float2 b0 = make_float2(Hre[c*NTT + o0], -Him[c*NTT + o0]);
    float2 b1 = make_float2(Hre[c*NTT + o1], -Him[c*NTT + o1]);
    __syncthreads();

    float2 cur0[8], cur1[8];
    // -------- forward: L (unit diag, lazy scaled) --------
    #pragma unroll
    for (int jj = 0; jj < 8; jj++){ cur0[jj] = BT[jj*NTT + r0]; cur1[jj] = BT[jj*NTT + r1]; }
    for (int ib = 0; ib < 16; ib++){
        float2 n0[8], n1[8];
        if (ib < 15){
            int nb = (ib + 1)*8;
            #pragma unroll
            for (int jj = 0; jj < 8; jj++){ n0[jj] = BT[(nb + jj)*NTT + r0]; n1[jj] = BT[(nb + jj)*NTT + r1]; }
        }
        #pragma unroll
        for (int jj = 0; jj < 8; jj++){
            int i = ib*8 + jj;
            float xr, xi;
            if (i < 64){ xr = __shfl(b0.x, i);      xi = __shfl(b0.y, i); }
            else       { xr = __shfl(b1.x, i - 64); xi = __shfl(b1.y, i - 64); }
            float2 rc = rc_s[i];
            float tr = rc.x*xr - rc.y*xi, ti = rc.x*xi + rc.y*xr;
            float2 l0 = cur0[jj], l1 = cur1[jj];
            if (r0 > i){ b0.x -= l0.x*tr - l0.y*ti; b0.y -= l0.x*ti + l0.y*tr; }
            if (r1 > i){ b1.x -= l1.x*tr - l1.y*ti; b1.y -= l1.x*ti + l1.y*tr; }
        }
        if (ib < 15){
            #pragma unroll
            for (int jj = 0; jj < 8; jj++){ cur0[jj] = n0[jj]; cur1[jj] = n1[jj]; }
        }
    }
    // -------- backward: U --------
    #pragma unroll
    for (int jj = 0; jj < 8; jj++){ cur0[jj] = BT[(120 + jj)*NTT + r0]; cur1[jj] = BT[(120 + jj)*NTT + r1]; }
    for (int ib = 15; ib >= 0; ib--){
        float2 n0[8], n1[8];
        if (ib > 0){
            int nb = (ib - 1)*8;
            #pragma unroll
            for (int jj = 0; jj < 8; jj++){ n0[jj] = BT[(nb + jj)*NTT + r0]; n1[jj] = BT[(nb + jj)*NTT + r1]; }
        }
        #pragma unroll
        for (int jj = 7; jj >= 0; jj--){
            int i = ib*8 + jj;
            float yr, yi;
            if (i < 64){ yr = __shfl(b0.x, i);      yi = __shfl(b0.y, i); }
            else       { yr = __shfl(b1.x, i - 64); yi = __shfl(b1.y, i - 64); }
            float2 rc = rc_s[i];
            float xr = rc.x*yr - rc.y*yi, xi = rc.x*yi + rc.y*yr;
            if (r0 == i){ b0.x = xr; b0.y = xi; }
            if (r1 == i){ b1.x = xr; b1.y = xi; }
            float2 u0 = cur0[jj], u1v = cur1[jj];
            if (r0 < i){ b0.x -= u0.x*xr - u0.y*xi; b0.y -= u0.x*xi + u0.y*xr; }
            if (r1 < i){ b1.x -= u1v.x*xr - u1v.y*xi; b1.y -= u1v.x*xi + u1v.y*xr; }
        }
        if (ib > 0){
            #pragma unroll
            for (int jj = 0; jj < 8; jj++){ cur0[jj] = n0[jj]; cur1[jj] = n1[jj]; }
        }
    }
    X[c*NTT + r0] = b0;
    X[c*NTT + r1] = b1;
}

// ---------------- streaming matvecs: y_k = vp2[k] x_k ; z_k = vp4[k] conj(h_k) ----------------
__global__ void k_matvec(const float* __restrict__ p2re, const float* __restrict__ p2im,
                         const float* __restrict__ p4re, const float* __restrict__ p4im,
                         const float2* __restrict__ X,
                         const float* __restrict__ Hre, const float* __restrict__ Him,
                         float2* __restrict__ Y, float2* __restrict__ Z)
{
    int b = blockIdx.x;
    int k = b >> 1, rh = b & 1;
    int t = threadIdx.x;
    __shared__ float2 xv[NTT], hv[NTT];
    if (t < NTT){
        xv[t] = X[k*NTT + t];
        hv[t] = make_float2(Hre[k*NTT + t], -Him[k*NTT + t]);
    }
    __syncthreads();
    int which = t >> 7, u = t & 127;
    int row = rh*64 + (u >> 1), ch = u & 1;
    size_t base = (size_t)k*16384 + (size_t)row*128 + (size_t)ch*64;
    const float* mre = (which ? p4re : p2re) + base;
    const float* mim = (which ? p4im : p2im) + base;
    const float2* vv = (which ? hv : xv) + ch*64;
    float ar = 0.f, ai = 0.f;
    #pragma unroll 4
    for (int cidx = 0; cidx < 64; cidx++){
        float r_ = mre[cidx], i_ = mim[cidx];
        float2 v = vv[cidx];
        ar += r_*v.x - i_*v.y;
        ai += r_*v.y + i_*v.x;
    }
    ar += __shfl_xor(ar, 1);
    ai += __shfl_xor(ai, 1);
    if (ch == 0){
        (which ? Z : Y)[k*NTT + row] = make_float2(ar, ai);
    }
}

// ---------------- combine (mid layers): Vn = s*(y + 0.01 z) + vp1 ; accumulate |Vn|^2 ----------------
__global__ void k_combine(const float2* __restrict__ Y, const float2* __restrict__ Z,
                          const float* __restrict__ sre, const float* __restrict__ sim,
                          const float* __restrict__ p1re, const float* __restrict__ p1im,
                          float2* __restrict__ VN, float* __restrict__ pw2)
{
    float acc = 0.f;
    for (int e = blockIdx.x*blockDim.x + threadIdx.x; e < KK*NTT; e += gridDim.x*blockDim.x){
        int k = e >> 7;
        c32 s = make_float2(sre[k], sim[k]);
        float2 y = Y[e], z = Z[e];
        y.x += 0.01f*z.x; y.y += 0.01f*z.y;
        c32 v = cmul(s, y);
        v.x += p1re[e]; v.y += p1im[e];
        VN[e] = v;
        acc += v.x*v.x + v.y*v.y;
    }
    __shared__ float red[4];
    for (int d = 32; d; d >>= 1) acc += __shfl_down(acc, d);
    int lane = threadIdx.x & 63, w = threadIdx.x >> 6;
    if (!lane) red[w] = acc;
    __syncthreads();
    if (!threadIdx.x) atomicAdd(pw2, red[0] + red[1] + red[2] + red[3]);
}

// ---------------- final layer: Vn = s * x ----------------
__global__ void k_finout(const float2* __restrict__ X,
                         const float* __restrict__ sre, const float* __restrict__ sim,
                         float2* __restrict__ VN, float* __restrict__ pw2)
{
    float acc = 0.f;
    for (int e = blockIdx.x*blockDim.x + threadIdx.x; e < KK*NTT; e += gridDim.x*blockDim.x){
        int k = e >> 7;
        c32 s = make_float2(sre[k], sim[k]);
        c32 v = cmul(s, X[e]);
        VN[e] = v;
        acc += v.x*v.x + v.y*v.y;
    }
    __shared__ float red[4];
    for (int d = 32; d; d >>= 1) acc += __shfl_down(acc, d);
    int lane = threadIdx.x & 63, w = threadIdx.x >> 6;
    if (!lane) red[w] = acc;
    __syncthreads();
    if (!threadIdx.x) atomicAdd(pw2, red[0] + red[1] + red[2] + red[3]);
}

// ---------------- output write (normalized, split planes) ----------------
__global__ void k_write(const float2* __restrict__ VN, const float* __restrict__ pw2,
                        float* __restrict__ out)
{
    float gsc = sqrtf(PMAXF / *pw2);
    for (int e = blockIdx.x*blockDim.x + threadIdx.x; e < KK*NTT; e += gridDim.x*blockDim.x){
        float2 v = VN[e];
        out[e] = gsc*v.x;
        out[KK*NTT + e] = gsc*v.y;
    }
}

extern "C" void kernel_launch(void* const* d_in, const int* in_sizes, int n_in,
                              void* d_out, int out_size, void* d_ws, size_t ws_size,
                              hipStream_t stream)
{
    const float* V0  = (const float*)d_in[0];
    const float* H   = (const float*)d_in[1];
    const float* mu1 = (const float*)d_in[2];
    const float* mu3 = (const float*)d_in[3];
    const float* mu4 = (const float*)d_in[4];
    const float* mw1 = (const float*)d_in[5];
    const float* mw3 = (const float*)d_in[6];
    const float* mv1 = (const float*)d_in[7];
    const float* mv2 = (const float*)d_in[8];
    const float* mv4 = (const float*)d_in[9];
    const float* fu1 = (const float*)d_in[10];
    const float* fu3 = (const float*)d_in[11];
    const float* fu4 = (const float*)d_in[12];
    const float* fw1 = (const float*)d_in[13];
    const float* fw3 = (const float*)d_in[14];

    float* ws = (float*)d_ws;
    float*  acc  = ws;                       // [9][4]: sumw_re, sumw_im, pw2, pad ; trvv at ws[40]
    float*  wre  = ws + 64;
    float*  wim  = ws + 192;
    float*  sre  = ws + 320;
    float*  sim  = ws + 448;
    float2* B    = (float2*)(ws + 1024);     // 16384 complex
    float2* rc   = (float2*)(ws + 33792);    // 128
    int*    perm = (int*)  (ws + 34048);     // 128
    float2* X    = (float2*)(ws + 34176);    // 16384
    float2* Y    = (float2*)(ws + 66944);    // 16384
    float2* Z    = (float2*)(ws + 99712);    // 16384
    float2* VN   = (float2*)(ws + 132480);   // 16384
    float2* BT   = (float2*)(ws + 165248);   // 16384

    const int LU_LDS = KK*LDA*sizeof(float2);   // 132,096 B dynamic
    (void)hipFuncSetAttribute((const void*)k_lu3,
                              hipFuncAttributeMaxDynamicSharedMemorySize, LU_LDS);

    hipMemsetAsync(ws, 0, 64*sizeof(float), stream);
    k_trvv<<<64, 256, 0, stream>>>(V0, ws + 40);

    const float* Hre = H;
    const float* Him = H + 16384;

    for (int l = 0; l < 9; l++){
        bool fin = (l == 8);
        const float* u1 = fin ? fu1 : mu1 + (size_t)l*256;
        const float* u3 = fin ? fu3 : mu3 + (size_t)l*256;
        const float* u4 = fin ? fu4 : mu4 + (size_t)l*256;
        const float* w1 = fin ? fw1 : mw1 + (size_t)l*256;
        const float* w3 = fin ? fw3 : mw3 + (size_t)l*256;

        k_stage1<<<128, 128, 0, stream>>>(Hre, Him, V0, V0 + 16384, VN, (l > 0) ? 1 : 0,
                                          (l > 0) ? (acc + (l - 1)*4 + 2) : nullptr,
                                          ws + 40,
                                          u1, u3, u4, w1, w3,
                                          wre, wim, sre, sim, acc + l*4);
        k_bbuild<<<128, 128, 0, stream>>>(Hre, Him, wre, wim, acc + l*4, B);
        k_lu3<<<1, 512, LU_LDS, stream>>>(B, BT, rc, perm);
        k_solve<<<128, 64, 0, stream>>>(BT, rc, perm, Hre, Him, X);

        if (!fin){
            const float* p2 = mv2 + (size_t)l*4194304;
            const float* p4 = mv4 + (size_t)l*4194304;
            const float* p1 = mv1 + (size_t)l*32768;
            k_matvec<<<256, 256, 0, stream>>>(p2, p2 + 2097152, p4, p4 + 2097152,
                                              X, Hre, Him, Y, Z);
            k_combine<<<64, 256, 0, stream>>>(Y, Z, sre, sim, p1, p1 + 16384,
                                              VN, acc + l*4 + 2);
        } else {
            k_finout<<<64, 256, 0, stream>>>(X, sre, sim, VN, acc + l*4 + 2);
            k_write<<<64, 256, 0, stream>>>(VN, acc + l*4 + 2, (float*)d_out);
        }
    }
}